// Round 13
// baseline (345.307 us; speedup 1.0000x reference)
//
#include <hip/hip_runtime.h>
#include <math.h>

typedef _Float16 half8 __attribute__((ext_vector_type(8)));
typedef _Float16 half2v __attribute__((ext_vector_type(2)));
typedef float floatx16 __attribute__((ext_vector_type(16)));
typedef float float2v __attribute__((ext_vector_type(2)));

constexpr float L2E = 1.4426950408889634f;

// ---------------- constants ----------------
constexpr float DLO[8] = {-0.010597401784997278f, 0.032883011666982945f, 0.030841381835986965f,
                          -0.18703481171888114f, -0.02798376941698385f, 0.6308807679295904f,
                          0.7148465705525415f, 0.23037781330885523f};
constexpr float DHI[8] = {-0.23037781330885523f, 0.7148465705525415f, -0.6308807679295904f,
                          -0.02798376941698385f, 0.18703481171888114f, 0.030841381835986965f,
                          -0.032883011666982945f, -0.010597401784997278f};

constexpr float CT21[21] = {
  1.0f,          0.95557281f,  0.82623877f,  0.62348980f,  0.36534102f,  0.07473009f,
  -0.22252093f, -0.5f,        -0.73305187f, -0.90096887f, -0.98883083f,
  -0.98883083f, -0.90096887f, -0.73305187f, -0.5f,        -0.22252093f,
  0.07473009f,   0.36534102f,  0.62348980f,  0.82623877f,  0.95557281f};
constexpr float ST21[21] = {
  0.0f,          0.29475517f,  0.56332006f,  0.78183148f,  0.93087375f,  0.99720380f,
  0.97492791f,   0.86602540f,  0.68017274f,  0.43388374f,  0.14904227f,
  -0.14904227f, -0.43388374f, -0.68017274f, -0.86602540f, -0.97492791f,
  -0.99720380f, -0.93087375f, -0.78183148f, -0.56332006f, -0.29475517f};

template<int N>
__device__ __forceinline__ void dwt_step(const float* in, float* a, float* d) {
  constexpr int NO = (N + 7) / 2;
#pragma unroll
  for (int i = 0; i < NO; i++) {
    float sa = 0.f, sd = 0.f;
#pragma unroll
    for (int j = 0; j < 8; j++) {
      int rel = 2 * i + j - 6;
      int idx = (rel < 0) ? (-rel - 1) : ((rel >= N) ? (2 * N - rel - 1) : rel);
      float v = in[idx];
      sa = fmaf(v, DLO[7 - j], sa);
      sd = fmaf(v, DHI[7 - j], sd);
    }
    a[i] = sa;
    d[i] = sd;
  }
}

// direct HBM->LDS 16B staging (m97 pattern: per-lane src, dst = uniform+lane*16)
__device__ __forceinline__ void gload_lds16(const void* g, void* l) {
  __builtin_amdgcn_global_load_lds(
      (const __attribute__((address_space(1))) unsigned int*)g,
      (__attribute__((address_space(3))) unsigned int*)l, 16, 0, 0);
}

// ---------------- kernel 1: features -> comb_t[b][s][88] fp16 ----------------
__global__ __launch_bounds__(256) void features_kernel(const float* __restrict__ x,
                                                       _Float16* __restrict__ comb_t) {
  __shared__ __align__(16) char smem[256 * 104 * 2];   // 53248B; unions xl (21504B)
  float* xl = (float*)smem;
  _Float16* hb = (_Float16*)smem;

  const int tid = threadIdx.x;
  const int g0 = blockIdx.x * 256;
  for (int idx = tid; idx < 256 * 21; idx += 256) xl[idx] = x[g0 * 21 + idx];
  __syncthreads();

  float xx[21];
#pragma unroll
  for (int t = 0; t < 21; t++) xx[t] = xl[tid * 21 + t];
  __syncthreads();   // all xl reads done before hb overwrites the region

  __align__(16) _Float16 hrow[88];
#pragma unroll
  for (int i = 78; i < 88; i++) hrow[i] = (_Float16)0.f;

#pragma unroll
  for (int t = 0; t < 21; t++) hrow[t] = (_Float16)xx[t];

#pragma unroll
  for (int k = 0; k < 11; k++) {
    float re = 0.f, im = 0.f;
#pragma unroll
    for (int t = 0; t < 21; t++) {
      const int m = (k * t) % 21;
      re = fmaf(xx[t], CT21[m], re);
      im = fmaf(xx[t], ST21[m], im);
    }
    hrow[21 + k] = (_Float16)sqrtf(re * re + im * im);
  }

  float a1[14], d1[14];
  dwt_step<21>(xx, a1, d1);
#pragma unroll
  for (int i = 0; i < 14; i++) hrow[64 + i] = (_Float16)d1[i];
  float a2[10], d2[10];
  dwt_step<14>(a1, a2, d2);
#pragma unroll
  for (int i = 0; i < 10; i++) hrow[54 + i] = (_Float16)d2[i];
  float a3[8], d3[8];
  dwt_step<10>(a2, a3, d3);
#pragma unroll
  for (int i = 0; i < 8; i++) hrow[46 + i] = (_Float16)d3[i];
  float a4[7], d4[7];
  dwt_step<8>(a3, a4, d4);
#pragma unroll
  for (int i = 0; i < 7; i++) {
    hrow[32 + i] = (_Float16)a4[i];
    hrow[39 + i] = (_Float16)d4[i];
  }

  // stage row to LDS (stride 104 fp16 = 208B, 16B-aligned)
  {
    uint4* hv = (uint4*)&hb[tid * 104];
    const uint4* srcv = (const uint4*)hrow;
#pragma unroll
    for (int i = 0; i < 11; i++) hv[i] = srcv[i];
  }
  __syncthreads();

  // coalesced writeout: 2816 uint4 chunks, lane i -> consecutive 16B
  uint4* dstv = (uint4*)(comb_t + (size_t)g0 * 88);
#pragma unroll
  for (int it = 0; it < 11; it++) {
    const int k = it * 256 + tid;       // 0..2815
    const int s = k / 11;
    const int e8 = k - s * 11;
    dstv[k] = *(const uint4*)&hb[s * 104 + e8 * 8];
  }
}

// ---------------- kernel 0: weight prep ----------------
__global__ __launch_bounds__(256) void wprep_kernel(const float* __restrict__ cw,
                                                    const float* __restrict__ w_ih,
                                                    const float* __restrict__ b_ih,
                                                    const float* __restrict__ b_hh,
                                                    _Float16* __restrict__ WbT,
                                                    _Float16* __restrict__ wih16,
                                                    float* __restrict__ biasI) {
  int idx = blockIdx.x * 256 + threadIdx.x;
  if (idx < 64 * 264) {
    int o = idx / 264, k = idx - o * 264;
    float v = 0.f;
    if (k < 240) {
      int dk = k / 80, c = k - dk * 80;
      if (c < 78) v = cw[o * 234 + c * 3 + dk];
    }
    WbT[idx] = (_Float16)v;
  } else if (idx < 16896 + 8192) {
    int j = idx - 16896;
    wih16[j] = (_Float16)(L2E * w_ih[j]);
  } else if (idx < 16896 + 8192 + 128) {
    int g = idx - 16896 - 8192;
    int p = ((g & 63) << 1) | (g >> 6);
    biasI[p] = L2E * (b_ih[g] + b_hh[g]);
  }
}

// ---------------- kernel 2: fused conv(MFMA)+pool+proj(MFMA) -> Xp ----------------
__global__ __launch_bounds__(256, 2) void conv_proj_kernel(const _Float16* __restrict__ comb_t,
                                                           const _Float16* __restrict__ WbT,
                                                           const float* __restrict__ cbias,
                                                           const _Float16* __restrict__ wih16,
                                                           const float* __restrict__ biasI,
                                                           float* __restrict__ Xp) {
  __shared__ __align__(16) char smem[61184];
  _Float16* At = (_Float16*)smem;
  _Float16* Bt = (_Float16*)(smem + 24576);
  _Float16* yt = (_Float16*)smem;
  _Float16* wl = (_Float16*)(smem + 9216);
  float* biasl = (float*)(smem + 27648);
  float* Xpt   = (float*)(smem + 28160);
  float* bl    = (float*)(smem + 60928);

  const int tid = threadIdx.x;
  const int b = blockIdx.y;
  const int s0 = blockIdx.x * 128;
  const int T0 = blockIdx.x * 64;

  // ---- phase A: stage conv inputs (direct HBM->LDS) ----
  {
    const char* srcA = (const char*)(comb_t + (size_t)((b << 10) + s0 - 1) * 88);
#pragma unroll
    for (int i = 0; i < 6; i++) {
      const int idx = i * 256 + tid;
      const int cidx = (idx < 1430) ? idx : 1429;
      gload_lds16(srcA + (size_t)cidx * 16, (char*)At + (size_t)idx * 16);
    }
    const char* srcB = (const char*)WbT;
#pragma unroll
    for (int i = 0; i < 8; i++) {
      const int idx = i * 256 + tid;
      gload_lds16(srcB + (size_t)idx * 16, (char*)Bt + (size_t)idx * 16);
    }
    if (tid < 64)
      gload_lds16(srcB + (size_t)(2048 + tid) * 16, (char*)Bt + (size_t)(2048 + tid) * 16);
  }
  if (tid < 64) bl[tid] = cbias[tid];
  __syncthreads();
  if (s0 == 0 && tid < 88) At[tid] = (_Float16)0.f;
  if (s0 == 896 && tid < 88) At[129 * 88 + tid] = (_Float16)0.f;
  __syncthreads();

  const int wave = tid >> 6, lane = tid & 63;
  const int ml = lane & 31;
  const int kg = lane >> 5;
  const int am = wave * 32 + ml;

  floatx16 acc0 = {};
  floatx16 acc1 = {};
#pragma unroll
  for (int ks = 0; ks < 15; ks++) {
    const int kb = ks * 16 + kg * 8;
    const int dk = (kb >= 160) ? 2 : ((kb >= 80) ? 1 : 0);
    const int c = kb - dk * 80;
    half8 av = *(const half8*)&At[(am + dk) * 88 + c];
    half8 bv0 = *(const half8*)&Bt[ml * 264 + kb];
    half8 bv1 = *(const half8*)&Bt[(32 + ml) * 264 + kb];
    acc0 = __builtin_amdgcn_mfma_f32_32x32x16_f16(av, bv0, acc0, 0, 0, 0);
    acc1 = __builtin_amdgcn_mfma_f32_32x32x16_f16(av, bv1, acc1, 0, 0, 0);
  }

  const float b0 = bl[ml], b1 = bl[32 + ml];
  float v0s[8], v1s[8];
#pragma unroll
  for (int p = 0; p < 8; p++) {
    v0s[p] = fmaxf(fmaxf(acc0[2 * p], acc0[2 * p + 1]) + b0, 0.f);
    v1s[p] = fmaxf(fmaxf(acc1[2 * p], acc1[2 * p + 1]) + b1, 0.f);
  }

  __syncthreads();

  // ---- phase B: y tile (fp16, stride 72) + w_ihT + bias ----
#pragma unroll
  for (int p = 0; p < 8; p++) {
    const int toff = (p & 1) + ((p >> 1) << 2);
    const int t = wave * 16 + (kg << 1) + toff;
    yt[t * 72 + ml] = (_Float16)v0s[p];
    yt[t * 72 + 32 + ml] = (_Float16)v1s[p];
  }
  for (int i = tid; i < 2048; i += 256) {
    int g = i >> 4, c4 = i & 15;
    *(uint2*)(wl + g * 72 + c4 * 4) = *(const uint2*)(wih16 + g * 64 + c4 * 4);
  }
  if (tid < 128) biasl[tid] = biasI[tid];
  __syncthreads();

  // ---- phase C: proj MFMA ----
  const int tm = wave & 1, tn0 = (wave >> 1) * 2;
  floatx16 pa0 = {};
  floatx16 pa1 = {};
#pragma unroll
  for (int kq = 0; kq < 4; kq++) {
    const int k0 = kq * 16 + kg * 8;
    half8 av = *(const half8*)&yt[(tm * 32 + ml) * 72 + k0];
    half8 bv0 = *(const half8*)&wl[(tn0 * 32 + ml) * 72 + k0];
    half8 bv1 = *(const half8*)&wl[((tn0 + 1) * 32 + ml) * 72 + k0];
    pa0 = __builtin_amdgcn_mfma_f32_32x32x16_f16(av, bv0, pa0, 0, 0, 0);
    pa1 = __builtin_amdgcn_mfma_f32_32x32x16_f16(av, bv1, pa1, 0, 0, 0);
  }

  {
    const int g0i = tn0 * 32 + ml;
    const int p0 = ((g0i & 63) << 1) | (g0i >> 6);   // interleaved gate layout
    const int g1i = (tn0 + 1) * 32 + ml;
    const int p1 = ((g1i & 63) << 1) | (g1i >> 6);
#pragma unroll
    for (int reg = 0; reg < 16; reg++) {
      const int row = (reg & 3) + 8 * (reg >> 2) + 4 * kg;
      const int m = tm * 32 + row;
      Xpt[m * 128 + p0] = pa0[reg];
      Xpt[m * 128 + p1] = pa1[reg];
    }
  }
  __syncthreads();

  float* xpg = Xp + ((size_t)b * 512 + T0) * 128;
  for (int i = tid; i < 2048; i += 256) {
    const int r = i >> 5, c4 = (i & 31) << 2;
    float4 v = *(float4*)&Xpt[r * 128 + c4];
    float4 bb = *(float4*)&biasl[c4];
    v.x += bb.x; v.y += bb.y; v.z += bb.z; v.w += bb.w;
    *(float4*)&xpg[r * 128 + c4] = v;
  }
}

// ---------------- kernel 3: LSTM recurrence + fc ----------------
// R13: matvec via v_dot2_f32_f16 — 2 fp16 MACs / 32-bit VOP3P instr (2-cyc
// issue) with FP32 accumulation. h broadcast as packed fp16 pairs: 1 cvt +
// 32 readlane (16-bit payload) + 16 scalar-pipe packs (dual-issued, ~free) +
// 32 fdot2. Matvec issue ~224 -> ~130 cyc/step. R9/R10 lesson: pk_fma_f32 is
// 64-bit data = 4-cyc issue (no win); dot2 is 32-bit data = real 2x.
__device__ __forceinline__ unsigned readlane_u(unsigned v, int k) {
  return __builtin_amdgcn_readlane(v, k);
}

#if __has_builtin(__builtin_amdgcn_exp2f)
#define EXP2F __builtin_amdgcn_exp2f
#else
#define EXP2F exp2f
#endif

#if __has_builtin(__builtin_amdgcn_permlane32_swap)
__device__ __forceinline__ float swap_half(float x) {
  auto r = __builtin_amdgcn_permlane32_swap(__float_as_uint(x), __float_as_uint(x),
                                            false, false);
  return __uint_as_float(r[1]);
}
#else
__device__ __forceinline__ float swap_half(float x) { return __shfl_down(x, 32); }
#endif

__device__ __forceinline__ void lstm_step(float& h, float& c, float2v xg,
                                          const half2v* __restrict__ wA2,
                                          const half2v* __restrict__ wB2, bool lo) {
  // phase 1: h -> fp16, broadcast, pack pairs on the scalar pipe
  _Float16 hh = (_Float16)h;
  unsigned hv = (unsigned)__builtin_bit_cast(unsigned short, hh);
  unsigned hp[16];
#pragma unroll
  for (int i = 0; i < 16; i++) {
    unsigned l16 = readlane_u(hv, 2 * i);
    unsigned h16 = readlane_u(hv, 2 * i + 1);
    hp[i] = l16 | (h16 << 16);          // SALU (s_lshl/s_or) on SGPR values
  }

  // phase 2: 32 fdot2 (fp32 acc), 4 independent chains
  float a0 = xg.x, a1 = 0.f, b0 = xg.y, b1 = 0.f;
#pragma unroll
  for (int i = 0; i < 16; i += 2) {
    half2v h0 = __builtin_bit_cast(half2v, hp[i]);
    half2v h1 = __builtin_bit_cast(half2v, hp[i + 1]);
    a0 = __builtin_amdgcn_fdot2(h0, wA2[i], a0, false);
    b0 = __builtin_amdgcn_fdot2(h0, wB2[i], b0, false);
    a1 = __builtin_amdgcn_fdot2(h1, wA2[i + 1], a1, false);
    b1 = __builtin_amdgcn_fdot2(h1, wB2[i + 1], b1, false);
  }
  const float gA = a0 + a1;            // pre-scaled by log2e
  const float gB = b0 + b1;

  float sA = __builtin_amdgcn_rcpf(1.0f + EXP2F(-gA));

  float argB = lo ? (gB + gB) : (-gB);
  float rB = __builtin_amdgcn_rcpf(EXP2F(argB) + 1.0f);
  float sB = lo ? fmaf(-2.f, rB, 1.f) : rB;

  float fv = swap_half(sA);
  float ov = swap_half(sB);
  c = fmaf(fv, c, sA * sB);            // c in true units (lanes<32)
  float rc = __builtin_amdgcn_rcpf(EXP2F(c * (2.f * L2E)) + 1.0f);
  float ov2 = ov + ov;
  h = fmaf(-ov2, rc, ov);              // h = ov * tanh(c)
}

__global__ __launch_bounds__(64, 1)
__attribute__((amdgpu_waves_per_eu(1, 1)))
void lstm_fc_kernel(const float* __restrict__ Xp,
                    const float* __restrict__ w_hh,
                    const float* __restrict__ fc_w,
                    const float* __restrict__ fc_b,
                    float* __restrict__ out) {
  const int b = blockIdx.x;
  const int L = threadIdx.x;
  const bool lo = (L < 32);

  // weights: rows L and L+64 of w_hh, scaled by log2e, packed fp16 pairs
  half2v wA2[16], wB2[16];
  {
    const float4* rA = (const float4*)(w_hh + L * 32);
    const float4* rB = (const float4*)(w_hh + (L + 64) * 32);
#pragma unroll
    for (int q = 0; q < 8; q++) {
      float4 a4 = rA[q], b4 = rB[q];
      wA2[2 * q]     = (half2v){(_Float16)(L2E * a4.x), (_Float16)(L2E * a4.y)};
      wA2[2 * q + 1] = (half2v){(_Float16)(L2E * a4.z), (_Float16)(L2E * a4.w)};
      wB2[2 * q]     = (half2v){(_Float16)(L2E * b4.x), (_Float16)(L2E * b4.y)};
      wB2[2 * q + 1] = (half2v){(_Float16)(L2E * b4.z), (_Float16)(L2E * b4.w)};
    }
  }

  const float* xp = Xp + (size_t)b * 512 * 128;
  float h = 0.f, c = 0.f;

  float2v p2[4];
#pragma unroll
  for (int u = 0; u < 4; u++) p2[u] = *(const float2v*)&xp[u * 128 + 2 * L];

  for (int t0 = 0; t0 < 512; t0 += 4) {
    float2v c2[4];
#pragma unroll
    for (int u = 0; u < 4; u++) c2[u] = p2[u];
    if (t0 + 4 < 512) {
#pragma unroll
      for (int u = 0; u < 4; u++)
        p2[u] = *(const float2v*)&xp[(t0 + 4 + u) * 128 + 2 * L];
    }
#pragma unroll
    for (int u = 0; u < 4; u++) lstm_step(h, c, c2[u], wA2, wB2, lo);
  }

  float v = lo ? h * fc_w[L & 31] : 0.f;
#pragma unroll
  for (int off = 32; off > 0; off >>= 1) v += __shfl_down(v, off);
  if (L == 0) out[b] = v + fc_b[0];
}

// ---------------- launch ----------------
extern "C" void kernel_launch(void* const* d_in, const int* in_sizes, int n_in,
                              void* d_out, int out_size, void* d_ws, size_t ws_size,
                              hipStream_t stream) {
  const float* x      = (const float*)d_in[0];  // [256,1024,21]
  const float* conv_w = (const float*)d_in[1];  // [64,78,3]
  const float* conv_b = (const float*)d_in[2];  // [64]
  const float* w_ih   = (const float*)d_in[3];  // [128,64]
  const float* w_hh   = (const float*)d_in[4];  // [128,32]
  const float* b_ih   = (const float*)d_in[5];  // [128]
  const float* b_hh   = (const float*)d_in[6];  // [128]
  const float* fc_w   = (const float*)d_in[7];  // [1,32]
  const float* fc_b   = (const float*)d_in[8];  // [1]
  float* out = (float*)d_out;                   // [256,1]

  char* wsb = (char*)d_ws;
  // [pad 256][comb_t 46,137,344][Xp 67,108,864][WbT 33,792][wih16 16,384][biasI 512]
  // pad: conv_proj stages row s=-1 for the first block (reads comb_t - 176 B).
  _Float16* comb_t = (_Float16*)(wsb + 256);
  float*    Xp     = (float*)(wsb + 256 + 46137344);
  _Float16* WbT    = (_Float16*)(wsb + 256 + 46137344 + 67108864);
  _Float16* wih16  = (_Float16*)(wsb + 256 + 46137344 + 67108864 + 33792);
  float*    biasI  = (float*)(wsb + 256 + 46137344 + 67108864 + 33792 + 16384);

  wprep_kernel<<<dim3(99), dim3(256), 0, stream>>>(conv_w, w_ih, b_ih, b_hh,
                                                   WbT, wih16, biasI);
  features_kernel<<<dim3(1024), dim3(256), 0, stream>>>(x, comb_t);
  conv_proj_kernel<<<dim3(8, 256), dim3(256), 0, stream>>>(comb_t, WbT, conv_b,
                                                           wih16, biasI, Xp);
  lstm_fc_kernel<<<dim3(256), dim3(64), 0, stream>>>(Xp, w_hh, fc_w, fc_b, out);
}

// Round 14
// 224.786 us; speedup vs baseline: 1.5362x; 1.5362x over previous
//
#include <hip/hip_runtime.h>
#include <math.h>

typedef _Float16 half8 __attribute__((ext_vector_type(8)));
typedef float floatx16 __attribute__((ext_vector_type(16)));
typedef float float2v __attribute__((ext_vector_type(2)));

constexpr float L2E = 1.4426950408889634f;

// ---------------- constants ----------------
constexpr float DLO[8] = {-0.010597401784997278f, 0.032883011666982945f, 0.030841381835986965f,
                          -0.18703481171888114f, -0.02798376941698385f, 0.6308807679295904f,
                          0.7148465705525415f, 0.23037781330885523f};
constexpr float DHI[8] = {-0.23037781330885523f, 0.7148465705525415f, -0.6308807679295904f,
                          -0.02798376941698385f, 0.18703481171888114f, 0.030841381835986965f,
                          -0.032883011666982945f, -0.010597401784997278f};

constexpr float CT21[21] = {
  1.0f,          0.95557281f,  0.82623877f,  0.62348980f,  0.36534102f,  0.07473009f,
  -0.22252093f, -0.5f,        -0.73305187f, -0.90096887f, -0.98883083f,
  -0.98883083f, -0.90096887f, -0.73305187f, -0.5f,        -0.22252093f,
  0.07473009f,   0.36534102f,  0.62348980f,  0.82623877f,  0.95557281f};
constexpr float ST21[21] = {
  0.0f,          0.29475517f,  0.56332006f,  0.78183148f,  0.93087375f,  0.99720380f,
  0.97492791f,   0.86602540f,  0.68017274f,  0.43388374f,  0.14904227f,
  -0.14904227f, -0.43388374f, -0.68017274f, -0.86602540f, -0.97492791f,
  -0.99720380f, -0.93087375f, -0.78183148f, -0.56332006f, -0.29475517f};

template<int N>
__device__ __forceinline__ void dwt_step(const float* in, float* a, float* d) {
  constexpr int NO = (N + 7) / 2;
#pragma unroll
  for (int i = 0; i < NO; i++) {
    float sa = 0.f, sd = 0.f;
#pragma unroll
    for (int j = 0; j < 8; j++) {
      int rel = 2 * i + j - 6;
      int idx = (rel < 0) ? (-rel - 1) : ((rel >= N) ? (2 * N - rel - 1) : rel);
      float v = in[idx];
      sa = fmaf(v, DLO[7 - j], sa);
      sd = fmaf(v, DHI[7 - j], sd);
    }
    a[i] = sa;
    d[i] = sd;
  }
}

// direct HBM->LDS 16B staging (m97 pattern: per-lane src, dst = uniform+lane*16)
__device__ __forceinline__ void gload_lds16(const void* g, void* l) {
  __builtin_amdgcn_global_load_lds(
      (const __attribute__((address_space(1))) unsigned int*)g,
      (__attribute__((address_space(3))) unsigned int*)l, 16, 0, 0);
}

// compute the 88-wide feature row for one (b,s) into hrow (fp16)
__device__ __forceinline__ void feature_row(const float* __restrict__ xr,
                                            _Float16* hrow) {
  float xx[21];
#pragma unroll
  for (int t = 0; t < 21; t++) xx[t] = xr[t];

#pragma unroll
  for (int i = 78; i < 88; i++) hrow[i] = (_Float16)0.f;

#pragma unroll
  for (int t = 0; t < 21; t++) hrow[t] = (_Float16)xx[t];

#pragma unroll
  for (int k = 0; k < 11; k++) {
    float re = 0.f, im = 0.f;
#pragma unroll
    for (int t = 0; t < 21; t++) {
      const int m = (k * t) % 21;
      re = fmaf(xx[t], CT21[m], re);
      im = fmaf(xx[t], ST21[m], im);
    }
    hrow[21 + k] = (_Float16)sqrtf(re * re + im * im);
  }

  float a1[14], d1[14];
  dwt_step<21>(xx, a1, d1);
#pragma unroll
  for (int i = 0; i < 14; i++) hrow[64 + i] = (_Float16)d1[i];
  float a2[10], d2[10];
  dwt_step<14>(a1, a2, d2);
#pragma unroll
  for (int i = 0; i < 10; i++) hrow[54 + i] = (_Float16)d2[i];
  float a3[8], d3[8];
  dwt_step<10>(a2, a3, d3);
#pragma unroll
  for (int i = 0; i < 8; i++) hrow[46 + i] = (_Float16)d3[i];
  float a4[7], d4[7];
  dwt_step<8>(a3, a4, d4);
#pragma unroll
  for (int i = 0; i < 7; i++) {
    hrow[32 + i] = (_Float16)a4[i];
    hrow[39 + i] = (_Float16)d4[i];
  }
}

// ---------------- kernel 0: weight prep ----------------
__global__ __launch_bounds__(256) void wprep_kernel(const float* __restrict__ cw,
                                                    const float* __restrict__ w_ih,
                                                    const float* __restrict__ b_ih,
                                                    const float* __restrict__ b_hh,
                                                    _Float16* __restrict__ WbT,
                                                    _Float16* __restrict__ wih16,
                                                    float* __restrict__ biasI) {
  int idx = blockIdx.x * 256 + threadIdx.x;
  if (idx < 64 * 264) {
    int o = idx / 264, k = idx - o * 264;
    float v = 0.f;
    if (k < 240) {
      int dk = k / 80, c = k - dk * 80;
      if (c < 78) v = cw[o * 234 + c * 3 + dk];
    }
    WbT[idx] = (_Float16)v;
  } else if (idx < 16896 + 8192) {
    int j = idx - 16896;
    wih16[j] = (_Float16)(L2E * w_ih[j]);
  } else if (idx < 16896 + 8192 + 128) {
    int g = idx - 16896 - 8192;
    int p = ((g & 63) << 1) | (g >> 6);
    biasI[p] = L2E * (b_ih[g] + b_hh[g]);
  }
}

// ---------------- kernel 1: fused features+conv(MFMA)+pool+proj(MFMA) -> Xp ----------------
// R14: features computed IN-BLOCK into the At LDS tile (threads 0..129, one
// feature row each) — kills the comb_t HBM round-trip (45MB write + 46MB read)
// and the separate features kernel. Halo rows recomputed (1.6% extra FLOP).
__global__ __launch_bounds__(256, 2) void conv_proj_kernel(const float* __restrict__ x,
                                                           const _Float16* __restrict__ WbT,
                                                           const float* __restrict__ cbias,
                                                           const _Float16* __restrict__ wih16,
                                                           const float* __restrict__ biasI,
                                                           float* __restrict__ Xp) {
  // phaseA: At[0,22880) feature rows, Bt[24576,58368)
  // phaseB: yt[0,9216) wl[9216,27648) biasl[27648,28160) Xpt[28160,60928)
  // bl [60928,61184) live whole kernel
  __shared__ __align__(16) char smem[61184];
  _Float16* At = (_Float16*)smem;
  _Float16* Bt = (_Float16*)(smem + 24576);
  _Float16* yt = (_Float16*)smem;
  _Float16* wl = (_Float16*)(smem + 9216);
  float* biasl = (float*)(smem + 27648);
  float* Xpt   = (float*)(smem + 28160);
  float* bl    = (float*)(smem + 60928);

  const int tid = threadIdx.x;
  const int b = blockIdx.y;
  const int s0 = blockIdx.x * 128;
  const int T0 = blockIdx.x * 64;

  // ---- phase A: stage conv weights (HBM->LDS, async) + compute features ----
  {
    const char* srcB = (const char*)WbT;
#pragma unroll
    for (int i = 0; i < 8; i++) {
      const int idx = i * 256 + tid;
      gload_lds16(srcB + (size_t)idx * 16, (char*)Bt + (size_t)idx * 16);
    }
    if (tid < 64)
      gload_lds16(srcB + (size_t)(2048 + tid) * 16, (char*)Bt + (size_t)(2048 + tid) * 16);
  }
  if (tid < 64) bl[tid] = cbias[tid];

  if (tid < 130) {
    const int s = s0 - 1 + tid;                    // row j=tid <-> s = s0-1+j
    __align__(16) _Float16 hrow[88];
    if (s < 0 || s > 1023) {
#pragma unroll
      for (int i = 0; i < 88; i++) hrow[i] = (_Float16)0.f;
    } else {
      feature_row(x + ((size_t)(b << 10) + s) * 21, hrow);
    }
    uint4* dst = (uint4*)&At[tid * 88];
    const uint4* src = (const uint4*)hrow;
#pragma unroll
    for (int i = 0; i < 11; i++) dst[i] = src[i];
  }
  __syncthreads();

  const int wave = tid >> 6, lane = tid & 63;
  const int ml = lane & 31;
  const int kg = lane >> 5;
  const int am = wave * 32 + ml;

  floatx16 acc0 = {};
  floatx16 acc1 = {};
#pragma unroll
  for (int ks = 0; ks < 15; ks++) {
    const int kb = ks * 16 + kg * 8;
    const int dk = (kb >= 160) ? 2 : ((kb >= 80) ? 1 : 0);
    const int c = kb - dk * 80;
    half8 av = *(const half8*)&At[(am + dk) * 88 + c];
    half8 bv0 = *(const half8*)&Bt[ml * 264 + kb];
    half8 bv1 = *(const half8*)&Bt[(32 + ml) * 264 + kb];
    acc0 = __builtin_amdgcn_mfma_f32_32x32x16_f16(av, bv0, acc0, 0, 0, 0);
    acc1 = __builtin_amdgcn_mfma_f32_32x32x16_f16(av, bv1, acc1, 0, 0, 0);
  }

  const float b0 = bl[ml], b1 = bl[32 + ml];
  float v0s[8], v1s[8];
#pragma unroll
  for (int p = 0; p < 8; p++) {
    v0s[p] = fmaxf(fmaxf(acc0[2 * p], acc0[2 * p + 1]) + b0, 0.f);
    v1s[p] = fmaxf(fmaxf(acc1[2 * p], acc1[2 * p + 1]) + b1, 0.f);
  }

  __syncthreads();

  // ---- phase B: y tile (fp16, stride 72) + w_ihT + bias ----
#pragma unroll
  for (int p = 0; p < 8; p++) {
    const int toff = (p & 1) + ((p >> 1) << 2);
    const int t = wave * 16 + (kg << 1) + toff;
    yt[t * 72 + ml] = (_Float16)v0s[p];
    yt[t * 72 + 32 + ml] = (_Float16)v1s[p];
  }
  for (int i = tid; i < 2048; i += 256) {
    int g = i >> 4, c4 = i & 15;
    *(uint2*)(wl + g * 72 + c4 * 4) = *(const uint2*)(wih16 + g * 64 + c4 * 4);
  }
  if (tid < 128) biasl[tid] = biasI[tid];
  __syncthreads();

  // ---- phase C: proj MFMA ----
  const int tm = wave & 1, tn0 = (wave >> 1) * 2;
  floatx16 pa0 = {};
  floatx16 pa1 = {};
#pragma unroll
  for (int kq = 0; kq < 4; kq++) {
    const int k0 = kq * 16 + kg * 8;
    half8 av = *(const half8*)&yt[(tm * 32 + ml) * 72 + k0];
    half8 bv0 = *(const half8*)&wl[(tn0 * 32 + ml) * 72 + k0];
    half8 bv1 = *(const half8*)&wl[((tn0 + 1) * 32 + ml) * 72 + k0];
    pa0 = __builtin_amdgcn_mfma_f32_32x32x16_f16(av, bv0, pa0, 0, 0, 0);
    pa1 = __builtin_amdgcn_mfma_f32_32x32x16_f16(av, bv1, pa1, 0, 0, 0);
  }

  {
    const int g0i = tn0 * 32 + ml;
    const int p0 = ((g0i & 63) << 1) | (g0i >> 6);   // interleaved gate layout
    const int g1i = (tn0 + 1) * 32 + ml;
    const int p1 = ((g1i & 63) << 1) | (g1i >> 6);
#pragma unroll
    for (int reg = 0; reg < 16; reg++) {
      const int row = (reg & 3) + 8 * (reg >> 2) + 4 * kg;
      const int m = tm * 32 + row;
      Xpt[m * 128 + p0] = pa0[reg];
      Xpt[m * 128 + p1] = pa1[reg];
    }
  }
  __syncthreads();

  float* xpg = Xp + ((size_t)b * 512 + T0) * 128;
  for (int i = tid; i < 2048; i += 256) {
    const int r = i >> 5, c4 = (i & 31) << 2;
    float4 v = *(float4*)&Xpt[r * 128 + c4];
    float4 bb = *(float4*)&biasl[c4];
    v.x += bb.x; v.y += bb.y; v.z += bb.z; v.w += bb.w;
    *(float4*)&xpg[r * 128 + c4] = v;
  }
}

// ---------------- kernel 2: LSTM recurrence + fc (exact R12 — best measured) ----------------
__device__ __forceinline__ float bcast_lane(float v, int k) {
  return __uint_as_float(__builtin_amdgcn_readlane(__float_as_uint(v), k));
}

#if __has_builtin(__builtin_amdgcn_exp2f)
#define EXP2F __builtin_amdgcn_exp2f
#else
#define EXP2F exp2f
#endif

#if __has_builtin(__builtin_amdgcn_permlane32_swap)
__device__ __forceinline__ float swap_half(float x) {
  auto r = __builtin_amdgcn_permlane32_swap(__float_as_uint(x), __float_as_uint(x),
                                            false, false);
  return __uint_as_float(r[1]);
}
#else
__device__ __forceinline__ float swap_half(float x) { return __shfl_down(x, 32); }
#endif

__device__ __forceinline__ void lstm_step(float& h, float& c, float2v xg,
                                          const float* __restrict__ wA,
                                          const float* __restrict__ wB, bool lo) {
  // phase 1: batched h-broadcast (32 independent v_readlane -> SGPRs)
  float hs[32];
#pragma unroll
  for (int k = 0; k < 32; k++) hs[k] = bcast_lane(h, k);

  // phase 2: scalar VOP3 fma matvec — 4 independent chains (AGPR-direct operands)
  float aA0 = xg.x, aA1 = 0.f, aB0 = xg.y, aB1 = 0.f;
#pragma unroll
  for (int k = 0; k < 32; k += 2) {
    aA0 = fmaf(hs[k], wA[k], aA0);
    aB0 = fmaf(hs[k], wB[k], aB0);
    aA1 = fmaf(hs[k + 1], wA[k + 1], aA1);
    aB1 = fmaf(hs[k + 1], wB[k + 1], aB1);
  }
  const float gA = aA0 + aA1;          // pre-scaled by log2e
  const float gB = aB0 + aB1;

  float sA = __builtin_amdgcn_rcpf(1.0f + EXP2F(-gA));

  float argB = lo ? (gB + gB) : (-gB);
  float rB = __builtin_amdgcn_rcpf(EXP2F(argB) + 1.0f);
  float sB = lo ? fmaf(-2.f, rB, 1.f) : rB;

  float fv = swap_half(sA);
  float ov = swap_half(sB);
  c = fmaf(fv, c, sA * sB);            // c in true units (lanes<32)
  float rc = __builtin_amdgcn_rcpf(EXP2F(c * (2.f * L2E)) + 1.0f);
  float ov2 = ov + ov;
  h = fmaf(-ov2, rc, ov);              // h = ov * tanh(c)
}

__global__ __launch_bounds__(64, 1)
__attribute__((amdgpu_waves_per_eu(1, 1)))
void lstm_fc_kernel(const float* __restrict__ Xp,
                    const float* __restrict__ w_hh,
                    const float* __restrict__ fc_w,
                    const float* __restrict__ fc_b,
                    float* __restrict__ out) {
  const int b = blockIdx.x;
  const int L = threadIdx.x;
  const bool lo = (L < 32);

  float wA[32], wB[32];
  {
    const float4* rA = (const float4*)(w_hh + L * 32);
    const float4* rB = (const float4*)(w_hh + (L + 64) * 32);
#pragma unroll
    for (int q = 0; q < 8; q++) {
      float4 a4 = rA[q], b4 = rB[q];
      wA[4 * q + 0] = L2E * a4.x; wA[4 * q + 1] = L2E * a4.y;
      wA[4 * q + 2] = L2E * a4.z; wA[4 * q + 3] = L2E * a4.w;
      wB[4 * q + 0] = L2E * b4.x; wB[4 * q + 1] = L2E * b4.y;
      wB[4 * q + 2] = L2E * b4.z; wB[4 * q + 3] = L2E * b4.w;
    }
  }

  const float* xp = Xp + (size_t)b * 512 * 128;
  float h = 0.f, c = 0.f;

  float2v p2[4];
#pragma unroll
  for (int u = 0; u < 4; u++) p2[u] = *(const float2v*)&xp[u * 128 + 2 * L];

  for (int t0 = 0; t0 < 512; t0 += 4) {
    float2v c2[4];
#pragma unroll
    for (int u = 0; u < 4; u++) c2[u] = p2[u];
    if (t0 + 4 < 512) {
#pragma unroll
      for (int u = 0; u < 4; u++)
        p2[u] = *(const float2v*)&xp[(t0 + 4 + u) * 128 + 2 * L];
    }
#pragma unroll
    for (int u = 0; u < 4; u++) lstm_step(h, c, c2[u], wA, wB, lo);
  }

  float v = lo ? h * fc_w[L & 31] : 0.f;
#pragma unroll
  for (int off = 32; off > 0; off >>= 1) v += __shfl_down(v, off);
  if (L == 0) out[b] = v + fc_b[0];
}

// ---------------- launch ----------------
extern "C" void kernel_launch(void* const* d_in, const int* in_sizes, int n_in,
                              void* d_out, int out_size, void* d_ws, size_t ws_size,
                              hipStream_t stream) {
  const float* x      = (const float*)d_in[0];  // [256,1024,21]
  const float* conv_w = (const float*)d_in[1];  // [64,78,3]
  const float* conv_b = (const float*)d_in[2];  // [64]
  const float* w_ih   = (const float*)d_in[3];  // [128,64]
  const float* w_hh   = (const float*)d_in[4];  // [128,32]
  const float* b_ih   = (const float*)d_in[5];  // [128]
  const float* b_hh   = (const float*)d_in[6];  // [128]
  const float* fc_w   = (const float*)d_in[7];  // [1,32]
  const float* fc_b   = (const float*)d_in[8];  // [1]
  float* out = (float*)d_out;                   // [256,1]

  char* wsb = (char*)d_ws;
  // [Xp 67,108,864][WbT 33,792][wih16 16,384][biasI 512]  (comb_t eliminated)
  float*    Xp    = (float*)wsb;
  _Float16* WbT   = (_Float16*)(wsb + 67108864);
  _Float16* wih16 = (_Float16*)(wsb + 67108864 + 33792);
  float*    biasI = (float*)(wsb + 67108864 + 33792 + 16384);

  wprep_kernel<<<dim3(99), dim3(256), 0, stream>>>(conv_w, w_ih, b_ih, b_hh,
                                                   WbT, wih16, biasI);
  conv_proj_kernel<<<dim3(8, 256), dim3(256), 0, stream>>>(x, WbT, conv_b,
                                                           wih16, biasI, Xp);
  lstm_fc_kernel<<<dim3(256), dim3(64), 0, stream>>>(Xp, w_hh, fc_w, fc_b, out);
}

// Round 15
// 199.350 us; speedup vs baseline: 1.7322x; 1.1276x over previous
//
#include <hip/hip_runtime.h>
#include <math.h>

typedef _Float16 half8 __attribute__((ext_vector_type(8)));
typedef float floatx16 __attribute__((ext_vector_type(16)));
typedef float float2v __attribute__((ext_vector_type(2)));

constexpr float L2E = 1.4426950408889634f;

// ---------------- constants ----------------
constexpr float DLO[8] = {-0.010597401784997278f, 0.032883011666982945f, 0.030841381835986965f,
                          -0.18703481171888114f, -0.02798376941698385f, 0.6308807679295904f,
                          0.7148465705525415f, 0.23037781330885523f};
constexpr float DHI[8] = {-0.23037781330885523f, 0.7148465705525415f, -0.6308807679295904f,
                          -0.02798376941698385f, 0.18703481171888114f, 0.030841381835986965f,
                          -0.032883011666982945f, -0.010597401784997278f};

constexpr float CT21[21] = {
  1.0f,          0.95557281f,  0.82623877f,  0.62348980f,  0.36534102f,  0.07473009f,
  -0.22252093f, -0.5f,        -0.73305187f, -0.90096887f, -0.98883083f,
  -0.98883083f, -0.90096887f, -0.73305187f, -0.5f,        -0.22252093f,
  0.07473009f,   0.36534102f,  0.62348980f,  0.82623877f,  0.95557281f};
constexpr float ST21[21] = {
  0.0f,          0.29475517f,  0.56332006f,  0.78183148f,  0.93087375f,  0.99720380f,
  0.97492791f,   0.86602540f,  0.68017274f,  0.43388374f,  0.14904227f,
  -0.14904227f, -0.43388374f, -0.68017274f, -0.86602540f, -0.97492791f,
  -0.99720380f, -0.93087375f, -0.78183148f, -0.56332006f, -0.29475517f};

template<int N>
__device__ __forceinline__ void dwt_step(const float* in, float* a, float* d) {
  constexpr int NO = (N + 7) / 2;
#pragma unroll
  for (int i = 0; i < NO; i++) {
    float sa = 0.f, sd = 0.f;
#pragma unroll
    for (int j = 0; j < 8; j++) {
      int rel = 2 * i + j - 6;
      int idx = (rel < 0) ? (-rel - 1) : ((rel >= N) ? (2 * N - rel - 1) : rel);
      float v = in[idx];
      sa = fmaf(v, DLO[7 - j], sa);
      sd = fmaf(v, DHI[7 - j], sd);
    }
    a[i] = sa;
    d[i] = sd;
  }
}

// direct HBM->LDS 16B staging (per-lane src affine in lane, dst = uniform+lane*16)
__device__ __forceinline__ void gload_lds16(const void* g, void* l) {
  __builtin_amdgcn_global_load_lds(
      (const __attribute__((address_space(1))) unsigned int*)g,
      (__attribute__((address_space(3))) unsigned int*)l, 16, 0, 0);
}

// compute the 88-wide feature row for one (b,s) into hrow (fp16)
__device__ __forceinline__ void feature_row(const float* __restrict__ xr,
                                            _Float16* hrow) {
  float xx[21];
#pragma unroll
  for (int t = 0; t < 21; t++) xx[t] = xr[t];

#pragma unroll
  for (int i = 78; i < 88; i++) hrow[i] = (_Float16)0.f;

#pragma unroll
  for (int t = 0; t < 21; t++) hrow[t] = (_Float16)xx[t];

#pragma unroll
  for (int k = 0; k < 11; k++) {
    float re = 0.f, im = 0.f;
#pragma unroll
    for (int t = 0; t < 21; t++) {
      const int m = (k * t) % 21;
      re = fmaf(xx[t], CT21[m], re);
      im = fmaf(xx[t], ST21[m], im);
    }
    hrow[21 + k] = (_Float16)sqrtf(re * re + im * im);
  }

  float a1[14], d1[14];
  dwt_step<21>(xx, a1, d1);
#pragma unroll
  for (int i = 0; i < 14; i++) hrow[64 + i] = (_Float16)d1[i];
  float a2[10], d2[10];
  dwt_step<14>(a1, a2, d2);
#pragma unroll
  for (int i = 0; i < 10; i++) hrow[54 + i] = (_Float16)d2[i];
  float a3[8], d3[8];
  dwt_step<10>(a2, a3, d3);
#pragma unroll
  for (int i = 0; i < 8; i++) hrow[46 + i] = (_Float16)d3[i];
  float a4[7], d4[7];
  dwt_step<8>(a3, a4, d4);
#pragma unroll
  for (int i = 0; i < 7; i++) {
    hrow[32 + i] = (_Float16)a4[i];
    hrow[39 + i] = (_Float16)d4[i];
  }
}

// ---------------- kernel 0: weight prep (unchanged) ----------------
__global__ __launch_bounds__(256) void wprep_kernel(const float* __restrict__ cw,
                                                    const float* __restrict__ w_ih,
                                                    const float* __restrict__ b_ih,
                                                    const float* __restrict__ b_hh,
                                                    _Float16* __restrict__ WbT,
                                                    _Float16* __restrict__ wih16,
                                                    float* __restrict__ biasI) {
  int idx = blockIdx.x * 256 + threadIdx.x;
  if (idx < 64 * 264) {
    int o = idx / 264, k = idx - o * 264;
    float v = 0.f;
    if (k < 240) {
      int dk = k / 80, c = k - dk * 80;
      if (c < 78) v = cw[o * 234 + c * 3 + dk];
    }
    WbT[idx] = (_Float16)v;
  } else if (idx < 16896 + 8192) {
    int j = idx - 16896;
    wih16[j] = (_Float16)(L2E * w_ih[j]);
  } else if (idx < 16896 + 8192 + 128) {
    int g = idx - 16896 - 8192;
    int p = ((g & 63) << 1) | (g >> 6);
    biasI[p] = L2E * (b_ih[g] + b_hh[g]);
  }
}

// ---------------- LSTM helpers (R12-exact) ----------------
__device__ __forceinline__ float bcast_lane(float v, int k) {
  return __uint_as_float(__builtin_amdgcn_readlane(__float_as_uint(v), k));
}

#if __has_builtin(__builtin_amdgcn_exp2f)
#define EXP2F __builtin_amdgcn_exp2f
#else
#define EXP2F exp2f
#endif

#if __has_builtin(__builtin_amdgcn_permlane32_swap)
__device__ __forceinline__ float swap_half(float x) {
  auto r = __builtin_amdgcn_permlane32_swap(__float_as_uint(x), __float_as_uint(x),
                                            false, false);
  return __uint_as_float(r[1]);
}
#else
__device__ __forceinline__ float swap_half(float x) { return __shfl_down(x, 32); }
#endif

__device__ __forceinline__ void lstm_step(float& h, float& c, float2v xg,
                                          const float* __restrict__ wA,
                                          const float* __restrict__ wB, bool lo) {
  float hs[32];
#pragma unroll
  for (int k = 0; k < 32; k++) hs[k] = bcast_lane(h, k);

  float aA0 = xg.x, aA1 = 0.f, aB0 = xg.y, aB1 = 0.f;
#pragma unroll
  for (int k = 0; k < 32; k += 2) {
    aA0 = fmaf(hs[k], wA[k], aA0);
    aB0 = fmaf(hs[k], wB[k], aB0);
    aA1 = fmaf(hs[k + 1], wA[k + 1], aA1);
    aB1 = fmaf(hs[k + 1], wB[k + 1], aB1);
  }
  const float gA = aA0 + aA1;          // pre-scaled by log2e
  const float gB = aB0 + aB1;

  float sA = __builtin_amdgcn_rcpf(1.0f + EXP2F(-gA));

  float argB = lo ? (gB + gB) : (-gB);
  float rB = __builtin_amdgcn_rcpf(EXP2F(argB) + 1.0f);
  float sB = lo ? fmaf(-2.f, rB, 1.f) : rB;

  float fv = swap_half(sA);
  float ov = swap_half(sB);
  c = fmaf(fv, c, sA * sB);            // c in true units (lanes<32)
  float rc = __builtin_amdgcn_rcpf(EXP2F(c * (2.f * L2E)) + 1.0f);
  float ov2 = ov + ov;
  h = fmaf(-ov2, rc, ov);              // h = ov * tanh(c)
}

// producer-wave barrier: 3 waves rendezvous on an LDS counter.
// s_waitcnt 0 drains this wave's global_load_lds / global stores before arrival;
// release/acquire gives cross-wave ordering (workgroup scope).
__device__ __forceinline__ void prod_barrier(int* pb, int& target) {
  target += 3;
  __builtin_amdgcn_s_waitcnt(0);
  if ((threadIdx.x & 63) == 0)
    __hip_atomic_fetch_add(pb, 1, __ATOMIC_RELEASE, __HIP_MEMORY_SCOPE_WORKGROUP);
  while (__hip_atomic_load(pb, __ATOMIC_ACQUIRE, __HIP_MEMORY_SCOPE_WORKGROUP) < target) {
  }
}

// ---------------- kernel 1: FUSED producer-consumer per batch ----------------
// One block per batch (grid 256). Wave 0 = LSTM consumer; waves 1-3 = producers
// computing Xp tiles (features -> conv MFMA -> pool -> proj MFMA -> global Xp).
// Forward-only sync: producers never wait on consumer (each Xp address written
// once, read once). Consumer spin-acquires `ready` per 64-step tile.
__global__ __launch_bounds__(256, 1)
__attribute__((amdgpu_waves_per_eu(1, 1)))
void fused_kernel(const float* __restrict__ x,
                  const _Float16* __restrict__ WbT,
                  const float* __restrict__ cbias,
                  const _Float16* __restrict__ wih16,
                  const float* __restrict__ biasI,
                  const float* __restrict__ w_hh,
                  const float* __restrict__ fc_w,
                  const float* __restrict__ fc_b,
                  float* __restrict__ Xp,
                  float* __restrict__ out) {
  // LDS layout (per tile, producers only): At[0,22880) Bt[24576,58368)
  // yt[0,9216) wl[9216,27648) biasl[27648,28160) Xpt[28160,60928) bl[60928,61184)
  __shared__ __align__(16) char smem[61184];
  __shared__ int ready;
  __shared__ int pbar;
  _Float16* At = (_Float16*)smem;
  _Float16* Bt = (_Float16*)(smem + 24576);
  _Float16* yt = (_Float16*)smem;
  _Float16* wl = (_Float16*)(smem + 9216);
  float* biasl = (float*)(smem + 27648);
  float* Xpt   = (float*)(smem + 28160);
  float* bl    = (float*)(smem + 60928);

  const int tid = threadIdx.x;
  const int b = blockIdx.x;

  if (tid == 0) { ready = 0; pbar = 0; }
  if (tid < 64) bl[tid] = cbias[tid];
  __syncthreads();   // ONLY full-block barrier; before wave specialization

  if (tid < 64) {
    // ================= consumer: LSTM + fc =================
    const int L = tid;
    const bool lo = (L < 32);
    float wA[32], wB[32];
    {
      const float4* rA = (const float4*)(w_hh + L * 32);
      const float4* rB = (const float4*)(w_hh + (L + 64) * 32);
#pragma unroll
      for (int q = 0; q < 8; q++) {
        float4 a4 = rA[q], b4 = rB[q];
        wA[4 * q + 0] = L2E * a4.x; wA[4 * q + 1] = L2E * a4.y;
        wA[4 * q + 2] = L2E * a4.z; wA[4 * q + 3] = L2E * a4.w;
        wB[4 * q + 0] = L2E * b4.x; wB[4 * q + 1] = L2E * b4.y;
        wB[4 * q + 2] = L2E * b4.z; wB[4 * q + 3] = L2E * b4.w;
      }
    }

    float h = 0.f, c = 0.f;
    for (int k = 0; k < 8; k++) {
      while (__hip_atomic_load(&ready, __ATOMIC_ACQUIRE, __HIP_MEMORY_SCOPE_WORKGROUP) < k + 1)
        __builtin_amdgcn_s_sleep(2);
      const float* xp = Xp + ((size_t)b * 512 + (size_t)k * 64) * 128;
      float2v p2[4];
#pragma unroll
      for (int u = 0; u < 4; u++) p2[u] = *(const float2v*)&xp[u * 128 + 2 * L];
      for (int t0 = 0; t0 < 64; t0 += 4) {
        float2v c2[4];
#pragma unroll
        for (int u = 0; u < 4; u++) c2[u] = p2[u];
        if (t0 + 4 < 64) {
#pragma unroll
          for (int u = 0; u < 4; u++)
            p2[u] = *(const float2v*)&xp[(t0 + 4 + u) * 128 + 2 * L];
        }
#pragma unroll
        for (int u = 0; u < 4; u++) lstm_step(h, c, c2[u], wA, wB, lo);
      }
    }

    float v = lo ? h * fc_w[L & 31] : 0.f;
#pragma unroll
    for (int off = 32; off > 0; off >>= 1) v += __shfl_down(v, off);
    if (L == 0) out[b] = v + fc_b[0];
  } else {
    // ================= producers: 3 waves, 8 tiles =================
    const int ptid = tid - 64;            // 0..191
    const int pw = (tid >> 6) - 1;        // producer wave id 0..2
    const int lane = tid & 63, ml = lane & 31, kg = lane >> 5;
    int bt = 0;                           // prod_barrier target

    for (int k = 0; k < 8; k++) {
      const int s0 = k * 128;

      // ---- phase A: async Bt restage + features -> At ----
      {
        const char* srcB = (const char*)WbT;
#pragma unroll
        for (int j = 0; j < 11; j++) {    // 2112 = 11*192 exactly
          const int idx = j * 192 + ptid;
          gload_lds16(srcB + (size_t)idx * 16, (char*)Bt + (size_t)idx * 16);
        }
      }
      if (ptid < 130) {
        const int s = s0 - 1 + ptid;      // row j=ptid <-> s = s0-1+j
        __align__(16) _Float16 hrow[88];
        if (s < 0 || s > 1023) {
#pragma unroll
          for (int i = 0; i < 88; i++) hrow[i] = (_Float16)0.f;
        } else {
          feature_row(x + ((size_t)(b << 10) + s) * 21, hrow);
        }
        uint4* dst = (uint4*)&At[ptid * 88];
        const uint4* src = (const uint4*)hrow;
#pragma unroll
        for (int i = 0; i < 11; i++) dst[i] = src[i];
      }
      prod_barrier(&pbar, bt);

      // ---- phase B: conv MFMA, 8 (mt,nt) wave-tiles over 3 waves ----
      float pooled[3][8];
      {
        int cc = 0;
        for (int wt = pw; wt < 8; wt += 3, cc++) {
          const int mt = wt & 3, nt = wt >> 2;
          floatx16 acc = {};
#pragma unroll
          for (int ks = 0; ks < 15; ks++) {
            const int kb = ks * 16 + kg * 8;
            const int dk = (kb >= 160) ? 2 : ((kb >= 80) ? 1 : 0);
            const int cofs = kb - dk * 80;
            half8 av = *(const half8*)&At[(mt * 32 + ml + dk) * 88 + cofs];
            half8 bv = *(const half8*)&Bt[(nt * 32 + ml) * 264 + kb];
            acc = __builtin_amdgcn_mfma_f32_32x32x16_f16(av, bv, acc, 0, 0, 0);
          }
          const float bo = bl[nt * 32 + ml];
#pragma unroll
          for (int p = 0; p < 8; p++)
            pooled[cc][p] = fmaxf(fmaxf(acc[2 * p], acc[2 * p + 1]) + bo, 0.f);
        }
      }
      prod_barrier(&pbar, bt);   // all conv reads of At/Bt done

      // ---- write yt (pooled fp16) + restage wl + biasl ----
      {
        int cc = 0;
        for (int wt = pw; wt < 8; wt += 3, cc++) {
          const int mt = wt & 3, nt = wt >> 2;
#pragma unroll
          for (int p = 0; p < 8; p++) {
            const int toff = (p & 1) + ((p >> 1) << 2);   // {0,1,4,5,8,9,12,13}
            const int t = mt * 16 + (kg << 1) + toff;
            yt[t * 72 + nt * 32 + ml] = (_Float16)pooled[cc][p];
          }
        }
        for (int i = ptid; i < 2048; i += 192) {
          int g = i >> 4, c4 = i & 15;
          *(uint2*)(wl + g * 72 + c4 * 4) = *(const uint2*)(wih16 + g * 64 + c4 * 4);
        }
        if (ptid < 128) biasl[ptid] = biasI[ptid];
      }
      prod_barrier(&pbar, bt);

      // ---- phase C: proj MFMA, 8 (pm,pn) tiles over 3 waves; scatter Xpt ----
      for (int wt = pw; wt < 8; wt += 3) {
        const int pm = wt & 1, pn = wt >> 1;
        floatx16 pa = {};
#pragma unroll
        for (int kq = 0; kq < 4; kq++) {
          const int k0 = kq * 16 + kg * 8;
          half8 av = *(const half8*)&yt[(pm * 32 + ml) * 72 + k0];
          half8 bv = *(const half8*)&wl[(pn * 32 + ml) * 72 + k0];
          pa = __builtin_amdgcn_mfma_f32_32x32x16_f16(av, bv, pa, 0, 0, 0);
        }
        const int gi = pn * 32 + ml;
        const int pp = ((gi & 63) << 1) | (gi >> 6);      // interleaved gate pos
#pragma unroll
        for (int reg = 0; reg < 16; reg++) {
          const int row = (reg & 3) + 8 * (reg >> 2) + 4 * kg;
          Xpt[(pm * 32 + row) * 128 + pp] = pa[reg];
        }
      }
      prod_barrier(&pbar, bt);

      // ---- coalesced Xp global writeout + bias ----
      {
        float* xpg = Xp + ((size_t)b * 512 + (size_t)k * 64) * 128;
        for (int i = ptid; i < 2048; i += 192) {
          const int r = i >> 5, c4 = (i & 31) << 2;
          float4 v = *(float4*)&Xpt[r * 128 + c4];
          float4 bb = *(float4*)&biasl[c4];
          v.x += bb.x; v.y += bb.y; v.z += bb.z; v.w += bb.w;
          *(float4*)&xpg[r * 128 + c4] = v;
        }
      }
      prod_barrier(&pbar, bt);   // all waves' Xp writes drained (s_waitcnt 0 + release)

      if (tid == 64)
        __hip_atomic_fetch_add(&ready, 1, __ATOMIC_RELEASE, __HIP_MEMORY_SCOPE_WORKGROUP);
    }
  }
}

// ---------------- launch ----------------
extern "C" void kernel_launch(void* const* d_in, const int* in_sizes, int n_in,
                              void* d_out, int out_size, void* d_ws, size_t ws_size,
                              hipStream_t stream) {
  const float* x      = (const float*)d_in[0];  // [256,1024,21]
  const float* conv_w = (const float*)d_in[1];  // [64,78,3]
  const float* conv_b = (const float*)d_in[2];  // [64]
  const float* w_ih   = (const float*)d_in[3];  // [128,64]
  const float* w_hh   = (const float*)d_in[4];  // [128,32]
  const float* b_ih   = (const float*)d_in[5];  // [128]
  const float* b_hh   = (const float*)d_in[6];  // [128]
  const float* fc_w   = (const float*)d_in[7];  // [1,32]
  const float* fc_b   = (const float*)d_in[8];  // [1]
  float* out = (float*)d_out;                   // [256,1]

  char* wsb = (char*)d_ws;
  // [Xp 67,108,864][WbT 33,792][wih16 16,384][biasI 512]
  float*    Xp    = (float*)wsb;
  _Float16* WbT   = (_Float16*)(wsb + 67108864);
  _Float16* wih16 = (_Float16*)(wsb + 67108864 + 33792);
  float*    biasI = (float*)(wsb + 67108864 + 33792 + 16384);

  wprep_kernel<<<dim3(99), dim3(256), 0, stream>>>(conv_w, w_ih, b_ih, b_hh,
                                                   WbT, wih16, biasI);
  fused_kernel<<<dim3(256), dim3(256), 0, stream>>>(x, WbT, conv_b, wih16, biasI,
                                                    w_hh, fc_w, fc_b, Xp, out);
}